// Round 6
// baseline (173.248 us; speedup 1.0000x reference)
//
#include <hip/hip_runtime.h>
#include <math.h>

// TemporalSNNClassifier — bit-exact fp32 emulation (absmax 0.0 since r2).
//
// r20: phase-B read dedup via v_permlane32_swap_b32. Falsified so far:
// w2 LDS reads (r18 null), x-delivery (r19 null). Survivor: pk read
// stream. Per CU per ts-group: 512 ds_read_b128 x ~12cyc = 6.1k cyc LDS
// pipe vs ~3.3k VALU/SIMD -> pipe 2x oversubscribed (VALUBusy 53% ✓).
// Half that traffic is duplication: lanes 32-63 read the SAME addresses
// as 0-31 (law: same-address b128 never dedups). Fix: low lanes read
// t-slots {0,1}, high lanes {2,3} (32 dense reads/wave), reconstruct all
// four via permlane32_swap(v,v): ret0 = low-half word (t01) broadcast,
// ret1 = high-half (t23). p0..p3 bit-identical -> chains untouched ->
// absmax 0.0 preserved. Swap cost rides the VALU, which has slack.
//
// r19: x via SMEM (s_load_dwordx4, wave-uniform indices) — time-null but
// kept (smaller LDS, no xcf). r17: fusion 66+66 -> 92.5us in-kernel;
// ~50us/iter harness floor outside kernel. r16b: fma_mix 82->66us.
// Unified law (r10+r12+m136): 16B-per-lane VECTOR reads NEVER dedup —
// wave-uniform b128 moves 64x16B serialized; b32 same-addr broadcast FREE.
//
// FROZEN numerics: k-ascending single-accumulator fmaf chains (GEMM1),
// h-ascending 0..127 chain per (row,class,t) via v_fma_mix_f32 over fp16
// spike pairs (exact for {0,1}, single f32 rounding == fmaf(spk,w,acc)),
// bias as one separate add, leaky update ((0.9f*mem)+cur)-reset with
// contraction off, spike <=> mem > 1.0f, reset_t == spk_{t-1}.

#define T_STEPS 64
#define IN_DIM  256
#define HID     128
#define NCLS    8

#define ROWS   32     // rows per block (both phases)
#define THR    256
#define A_KQ   16     // float4 k-quads per chunk (64 k)
#define RSTR   260    // pk row stride (u32); =4 mod 32 -> staggered banks

typedef float f32x4 __attribute__((ext_vector_type(4)));
typedef unsigned int u32x2 __attribute__((ext_vector_type(2)));

// pack two {0.0f,1.0f} spikes into one u32 as fp16 pair (lo=a, hi=b).
static __device__ __forceinline__ unsigned int pkspk(float a, float b) {
    auto h = __builtin_amdgcn_cvt_pkrtz(a, b);   // __fp16 ext_vector(2), 4B
    return __builtin_bit_cast(unsigned int, h);
}

// permlane32_swap(v,v): lo = v[lane&31] (low-half word, all lanes),
//                       hi = v[32|(lane&31)] (high-half word, all lanes).
static __device__ __forceinline__ void lane_swap(unsigned int v,
                                                 unsigned int& lo,
                                                 unsigned int& hi) {
#if __has_builtin(__builtin_amdgcn_permlane32_swap)
    u32x2 r = __builtin_amdgcn_permlane32_swap(v, v, false, false);
    lo = r.x; hi = r.y;
#else
    unsigned int a, b;
    asm("v_mov_b32 %0, %2\n\t"
        "v_mov_b32 %1, %2\n\t"
        "v_permlane32_swap_b32 %0, %1"
        : "=&v"(a), "=&v"(b) : "v"(v));
    lo = a; hi = b;
#endif
}

__global__ __launch_bounds__(THR, 2)
void snn_fused(const float* __restrict__ x, const float* __restrict__ W1,
               const float* __restrict__ b1, const float* __restrict__ W2,
               const float* __restrict__ b2, float* __restrict__ out)
{
#pragma clang fp contract(off)
    __shared__ __align__(16) char smem[33280];
    float4 (* const w1c)[HID + 2] = (float4 (*)[HID + 2])smem;   // [16][130]
    unsigned int* const pk  = (unsigned int*)smem;               // 32*260
    float*        const wsl = (float*)smem;                      // 32*128

    const int tid  = threadIdx.x;
    const int lane = tid & 63;

    // ================= phase 1: cur1 GEMM (x via SMEM, r19) ==============
    {
        const int wv = __builtin_amdgcn_readfirstlane(tid >> 6);   // 0..3
        const size_t rowg0 = (size_t)blockIdx.x * ROWS;
        // per-wave x base: rows wv*8 .. wv*8+7 (uniform)
        const float* xb = x + (rowg0 + (size_t)wv * 8) * IN_DIM;

        float accL[8], accH[8];
        #pragma unroll
        for (int j = 0; j < 8; ++j) { accL[j] = 0.0f; accH[j] = 0.0f; }

        #pragma unroll 1
        for (int ch = 0; ch < 4; ++ch) {
            const int kbase = ch * (A_KQ * 4);
            // stage W1 chunk: 2048 float4, 8 per thread (coalesced per h-row)
            #pragma unroll
            for (int s = 0; s < 8; ++s) {
                const int idx = tid + s * THR;
                const int h = idx >> 4, kq = idx & 15;
                w1c[kq][h] = *(const float4*)(W1 + (size_t)h * IN_DIM + kbase + kq * 4);
            }
            __syncthreads();

            const float* xbc = xb + kbase;
            #pragma unroll 4
            for (int kq = 0; kq < A_KQ; ++kq) {
                // 8 rows' k-quads for this kq -> SGPRs (one wait for all 8).
                const float* xkq = xbc + kq * 4;
                f32x4 q0, q1, q2, q3, q4, q5, q6, q7;
                asm volatile(
                    "s_load_dwordx4 %0, %8, 0x0\n\t"
                    "s_load_dwordx4 %1, %8, 0x400\n\t"
                    "s_load_dwordx4 %2, %8, 0x800\n\t"
                    "s_load_dwordx4 %3, %8, 0xc00\n\t"
                    "s_load_dwordx4 %4, %8, 0x1000\n\t"
                    "s_load_dwordx4 %5, %8, 0x1400\n\t"
                    "s_load_dwordx4 %6, %8, 0x1800\n\t"
                    "s_load_dwordx4 %7, %8, 0x1c00\n\t"
                    "s_waitcnt lgkmcnt(0)"
                    : "=&s"(q0), "=&s"(q1), "=&s"(q2), "=&s"(q3),
                      "=&s"(q4), "=&s"(q5), "=&s"(q6), "=&s"(q7)
                    : "s"(xkq));

                const float4 wL = w1c[kq][lane];        // lane-contig 1KB
                const float4 wH = w1c[kq][64 + lane];
                // k ascending, single acc per (row, h) — order unchanged.
#define ROWFMA(J, XQ) { \
                float aL = accL[J], aH = accH[J]; \
                aL = fmaf(XQ.x, wL.x, aL); \
                aL = fmaf(XQ.y, wL.y, aL); \
                aL = fmaf(XQ.z, wL.z, aL); \
                aL = fmaf(XQ.w, wL.w, aL); \
                aH = fmaf(XQ.x, wH.x, aH); \
                aH = fmaf(XQ.y, wH.y, aH); \
                aH = fmaf(XQ.z, wH.z, aH); \
                aH = fmaf(XQ.w, wH.w, aH); \
                accL[J] = aL; accH[J] = aH; }
                ROWFMA(0, q0) ROWFMA(1, q1) ROWFMA(2, q2) ROWFMA(3, q3)
                ROWFMA(4, q4) ROWFMA(5, q5) ROWFMA(6, q6) ROWFMA(7, q7)
#undef ROWFMA
            }
            __syncthreads();   // w1c consumed before re-stage / alias
        }

        // handoff: cur1 tile -> LDS (aliases dead w1c). Values bit-identical
        // to the old global ws path (same accL/accH + one rounded bias add).
        const float bL = b1[lane], bH = b1[64 + lane];
        #pragma unroll
        for (int j = 0; j < 8; ++j) {
            const int rr = wv * 8 + j;
            wsl[rr * HID + lane]      = accL[j] + bL;
            wsl[rr * HID + 64 + lane] = accH[j] + bH;
        }
    }

    // ================= phase 2: temporal loop =============
    const int r = tid >> 3;            // phase-a row 0..31
    const int q = tid & 7;             // phase-a h-block

    const int brow = lane & 31;
    const int bcls = 2 * (tid >> 6) + (lane >> 5);
    const float b2c = b2[bcls];

    // W2 row for this thread's class -> VGPRs (grid-limited 2 waves/SIMD,
    // so up to 256 VGPR/thread is free).
    float4 w2r[32];
    {
        const float4* wg = (const float4*)(W2 + bcls * HID);
        #pragma unroll
        for (int g = 0; g < 32; ++g) w2r[g] = wg[g];
    }

    __syncthreads();   // wsl writes visible

    float cur1[16];
    {
        const float* src = wsl + r * HID + q * 16;
        #pragma unroll
        for (int i = 0; i < 4; ++i) {
            const float4 v = *(const float4*)(src + 4 * i);
            cur1[4*i+0] = v.x; cur1[4*i+1] = v.y;
            cur1[4*i+2] = v.z; cur1[4*i+3] = v.w;
        }
    }
    __syncthreads();   // cur1 read complete before pk overwrites wsl region

    float mem1[16], spk1[16];
    #pragma unroll
    for (int i = 0; i < 16; ++i) { mem1[i] = 0.0f; spk1[i] = 0.0f; }
    float m2 = 0.0f, r2v = 0.0f, o = 0.0f;

    #pragma unroll 1
    for (int ts = 0; ts < T_STEPS; ts += 4) {
        #pragma unroll
        for (int j = 0; j < 4; ++j) {
            #pragma unroll
            for (int i = 0; i < 16; ++i) {
                float tmp = 0.9f * mem1[i];   // rounded mul
                tmp = tmp + cur1[i];          // rounded add
                float m = tmp - spk1[i];      // rounded sub
                mem1[i] = m;
                spk1[i] = (m > 1.0f) ? 1.0f : 0.0f;
            }
            unsigned int* dst = &pk[r * RSTR + j * 64 + q * 8];
            #pragma unroll
            for (int s = 0; s < 2; ++s) {
                uint4 pv;
                pv.x = pkspk(spk1[8*s+0], spk1[8*s+1]);   // lo=even h, hi=odd h
                pv.y = pkspk(spk1[8*s+2], spk1[8*s+3]);
                pv.z = pkspk(spk1[8*s+4], spk1[8*s+5]);
                pv.w = pkspk(spk1[8*s+6], spk1[8*s+7]);
                *(uint4*)(dst + 4 * s) = pv;
            }
        }
        __syncthreads();

        float a0 = 0.0f, a1 = 0.0f, a2 = 0.0f, a3 = 0.0f;
        // dedup'd reads: low lanes fetch t-slots {0,1}, high lanes {2,3};
        // permlane32_swap reconstructs p0..p3 (bit-identical words).
        const int thi = (lane >> 4) & 2;     // 0 for lanes 0-31, 2 for 32-63
        const unsigned int* srcT = &pk[brow * RSTR + thi * 64];
        // v_fma_mix_f32: src0 = fp16 half of packed word (exact 0/1 -> f32),
        // src1 = f32 W2 (VGPR), src2 = f32 acc; single f32 rounding —
        // bit-identical to fmaf(spk, w, acc), h-ascending. LO=even h, HI=odd.
#define FMIX_LO(A, P, W) \
        asm("v_fma_mix_f32 %0, %1, %2, %0 op_sel_hi:[1,0,0]" \
            : "+v"(A) : "v"(P), "v"(W));
#define FMIX_HI(A, P, W) \
        asm("v_fma_mix_f32 %0, %1, %2, %0 op_sel:[1,0,0] op_sel_hi:[1,0,0]" \
            : "+v"(A) : "v"(P), "v"(W));
#define TR(A, P) \
        FMIX_LO(A, P.x, wA.x) FMIX_HI(A, P.x, wA.y) \
        FMIX_LO(A, P.y, wA.z) FMIX_HI(A, P.y, wA.w) \
        FMIX_LO(A, P.z, wB.x) FMIX_HI(A, P.z, wB.y) \
        FMIX_LO(A, P.w, wB.z) FMIX_HI(A, P.w, wB.w)
        #pragma unroll
        for (int gg = 0; gg < 16; ++gg) {
            const uint4 ra = *(const uint4*)(srcT + 4 * gg);        // slot thi
            const uint4 rb = *(const uint4*)(srcT + 64 + 4 * gg);   // slot thi+1
            uint4 p0, p1, p2, p3;
            lane_swap(ra.x, p0.x, p2.x); lane_swap(ra.y, p0.y, p2.y);
            lane_swap(ra.z, p0.z, p2.z); lane_swap(ra.w, p0.w, p2.w);
            lane_swap(rb.x, p1.x, p3.x); lane_swap(rb.y, p1.y, p3.y);
            lane_swap(rb.z, p1.z, p3.z); lane_swap(rb.w, p1.w, p3.w);
            const float4 wA = w2r[2 * gg];
            const float4 wB = w2r[2 * gg + 1];
            TR(a0, p0) TR(a1, p1) TR(a2, p2) TR(a3, p3)
        }
#undef TR
#undef FMIX_HI
#undef FMIX_LO
        __syncthreads();

        const float aa[4] = {a0, a1, a2, a3};
        #pragma unroll
        for (int j = 0; j < 4; ++j) {
            const float c2 = aa[j] + b2c;
            float t2 = 0.9f * m2; t2 = t2 + c2; m2 = t2 - r2v;
            r2v = (m2 > 1.0f) ? 1.0f : 0.0f;
            o = o + r2v;
        }
    }

    out[((size_t)blockIdx.x * ROWS + brow) * NCLS + bcls] = o;
}

extern "C" void kernel_launch(void* const* d_in, const int* in_sizes, int n_in,
                              void* d_out, int out_size, void* d_ws, size_t ws_size,
                              hipStream_t stream) {
    const float* x  = (const float*)d_in[0];
    const float* W1 = (const float*)d_in[1];
    const float* b1 = (const float*)d_in[2];
    const float* W2 = (const float*)d_in[3];
    const float* b2 = (const float*)d_in[4];
    float* out = (float*)d_out;
    (void)d_ws; (void)ws_size;

    const int batch = in_sizes[0] / IN_DIM;          // 16384
    snn_fused<<<batch / ROWS, THR, 0, stream>>>(x, W1, b1, W2, b2, out);
}

// Round 8
// 152.564 us; speedup vs baseline: 1.1356x; 1.1356x over previous
//
#include <hip/hip_runtime.h>
#include <math.h>

// TemporalSNNClassifier — bit-exact fp32 emulation (absmax 0.0 since r2).
//
// r22: r21 occupancy structure (4 blocks/CU) with the twin exchange done
// via __shfl_xor(32) instead of permlane32_swap. r21 failed absmax 8.0;
// all index spaces re-traced clean; the exchange primitive is the one
// component resting on interpreted semantics -> replace with the boring
// battle-tested primitive and let HW adjudicate. Exchanged values are
// bit-copies; both twins run the identical frozen layer-2 chain.
// PRE-COMMIT: if this also fails, the blind spot is in the rescales ->
// next round reverts to r19-exact (verified 90us).
//
// Structure (r21): ROWS 16, 1024 blocks = 4 blocks/CU = 4 waves/SIMD
// (launch_bounds(256,4)); arena 33280B x4 = 133KB <= 160KB. Phase-b
// thread = (row, cls, tpair) computes 2 of 4 t-chains (halves per-thread
// LDS reads; per-CU pipe totals conserved, overlap doubles). Rationale:
// 1 thread/chain pins 2 waves/SIMD for ANY rows/block (chains = 131072
// threads exactly); only 2 threads/chain reaches 4.
//
// Falsified: w2 reads (r18 null), x-delivery (r19 null), pk lane-dedup
// at 2 blocks (r20 NEGATIVE: spills). r19: x via SMEM — kept (no xcf).
// r17: fusion 66+66 -> 92.5us. r16b: fma_mix 82->66us. Unified law
// (r10+r12+m136): 16B-per-lane VECTOR reads NEVER dedup; b32 same-addr
// broadcast FREE.
//
// FROZEN numerics: k-ascending single-accumulator fmaf chains (GEMM1),
// h-ascending 0..127 chain per (row,class,t) via v_fma_mix_f32 over fp16
// spike pairs (exact for {0,1}, single f32 rounding == fmaf(spk,w,acc)),
// bias as one separate add, leaky update ((0.9f*mem)+cur)-reset with
// contraction off, spike <=> mem > 1.0f, reset_t == spk_{t-1}.

#define T_STEPS 64
#define IN_DIM  256
#define HID     128
#define NCLS    8

#define ROWS   16     // rows per block (both phases)
#define THR    256
#define A_KQ   16     // float4 k-quads per chunk (64 k)
#define RSTR   260    // pk row stride (u32); =4 mod 32 -> staggered banks

typedef float f32x4 __attribute__((ext_vector_type(4)));

// pack two {0.0f,1.0f} spikes into one u32 as fp16 pair (lo=a, hi=b).
static __device__ __forceinline__ unsigned int pkspk(float a, float b) {
    auto h = __builtin_amdgcn_cvt_pkrtz(a, b);   // __fp16 ext_vector(2), 4B
    return __builtin_bit_cast(unsigned int, h);
}

__global__ __launch_bounds__(THR, 4)
void snn_fused(const float* __restrict__ x, const float* __restrict__ W1,
               const float* __restrict__ b1, const float* __restrict__ W2,
               const float* __restrict__ b2, float* __restrict__ out)
{
#pragma clang fp contract(off)
    __shared__ __align__(16) char smem[33280];
    float4 (* const w1c)[HID + 2] = (float4 (*)[HID + 2])smem;   // [16][130]
    unsigned int* const pk  = (unsigned int*)smem;               // 16*260 u32
    float4*       const w2l = (float4*)(smem + 16640);           // 256 float4
    float*        const wsl = (float*)smem;                      // 16*128 f32

    const int tid  = threadIdx.x;
    const int lane = tid & 63;

    // ================= phase 1: cur1 GEMM (x via SMEM, r19) ==============
    {
        const int wv = __builtin_amdgcn_readfirstlane(tid >> 6);   // 0..3
        const size_t rowg0 = (size_t)blockIdx.x * ROWS;
        // per-wave x base: rows wv*4 .. wv*4+3 (uniform)
        const float* xb = x + (rowg0 + (size_t)wv * 4) * IN_DIM;

        float accL[4], accH[4];
        #pragma unroll
        for (int j = 0; j < 4; ++j) { accL[j] = 0.0f; accH[j] = 0.0f; }

        #pragma unroll 1
        for (int ch = 0; ch < 4; ++ch) {
            const int kbase = ch * (A_KQ * 4);
            // stage W1 chunk: 2048 float4, 8 per thread (coalesced per h-row)
            #pragma unroll
            for (int s = 0; s < 8; ++s) {
                const int idx = tid + s * THR;
                const int h = idx >> 4, kq = idx & 15;
                w1c[kq][h] = *(const float4*)(W1 + (size_t)h * IN_DIM + kbase + kq * 4);
            }
            __syncthreads();

            const float* xbc = xb + kbase;
            #pragma unroll 4
            for (int kq = 0; kq < A_KQ; ++kq) {
                // 4 rows' k-quads for this kq -> SGPRs (one wait for all 4).
                const float* xkq = xbc + kq * 4;
                f32x4 q0, q1, q2, q3;
                asm volatile(
                    "s_load_dwordx4 %0, %4, 0x0\n\t"
                    "s_load_dwordx4 %1, %4, 0x400\n\t"
                    "s_load_dwordx4 %2, %4, 0x800\n\t"
                    "s_load_dwordx4 %3, %4, 0xc00\n\t"
                    "s_waitcnt lgkmcnt(0)"
                    : "=&s"(q0), "=&s"(q1), "=&s"(q2), "=&s"(q3)
                    : "s"(xkq));

                const float4 wL = w1c[kq][lane];        // lane-contig 1KB
                const float4 wH = w1c[kq][64 + lane];
                // k ascending, single acc per (row, h) — order unchanged.
#define ROWFMA(J, XQ) { \
                float aL = accL[J], aH = accH[J]; \
                aL = fmaf(XQ.x, wL.x, aL); \
                aL = fmaf(XQ.y, wL.y, aL); \
                aL = fmaf(XQ.z, wL.z, aL); \
                aL = fmaf(XQ.w, wL.w, aL); \
                aH = fmaf(XQ.x, wH.x, aH); \
                aH = fmaf(XQ.y, wH.y, aH); \
                aH = fmaf(XQ.z, wH.z, aH); \
                aH = fmaf(XQ.w, wH.w, aH); \
                accL[J] = aL; accH[J] = aH; }
                ROWFMA(0, q0) ROWFMA(1, q1) ROWFMA(2, q2) ROWFMA(3, q3)
#undef ROWFMA
            }
            __syncthreads();   // w1c consumed before re-stage / alias
        }

        // handoff: cur1 tile -> LDS (aliases dead w1c). Values bit-identical
        // (same accL/accH + one rounded bias add). Also stage W2 (region
        // aliases dead w1c bytes 16640+, disjoint from wsl and pk).
        const float bL = b1[lane], bH = b1[64 + lane];
        #pragma unroll
        for (int j = 0; j < 4; ++j) {
            const int rr = wv * 4 + j;
            wsl[rr * HID + lane]      = accL[j] + bL;
            wsl[rr * HID + 64 + lane] = accH[j] + bH;
        }
        w2l[tid] = ((const float4*)W2)[tid];
    }
    __syncthreads();

    // ================= phase 2: temporal loop =============
    const int r = tid >> 4;            // phase-a row 0..15
    const int q = tid & 15;            // phase-a h-block (8 h each)

    float cur1[8];
    {
        const float* src = wsl + r * HID + q * 8;
        #pragma unroll
        for (int i = 0; i < 2; ++i) {
            const float4 v = *(const float4*)(src + 4 * i);
            cur1[4*i+0] = v.x; cur1[4*i+1] = v.y;
            cur1[4*i+2] = v.z; cur1[4*i+3] = v.w;
        }
    }
    __syncthreads();   // cur1 read complete before pk overwrites wsl region

    const int brow  = lane & 15;
    const int u     = lane >> 4;                 // 0..3
    const bool hihalf = (lane >= 32);            // tpair==1
    const int bcls  = 2 * (tid >> 6) + (u & 1);  // class 0..7
    const float b2c = b2[bcls];
    const float4* __restrict__ w2p = &w2l[bcls * 32];

    float mem1[8], spk1[8];
    #pragma unroll
    for (int i = 0; i < 8; ++i) { mem1[i] = 0.0f; spk1[i] = 0.0f; }
    float m2 = 0.0f, r2v = 0.0f, o = 0.0f;

    #pragma unroll 1
    for (int ts = 0; ts < T_STEPS; ts += 4) {
        #pragma unroll
        for (int j = 0; j < 4; ++j) {
            #pragma unroll
            for (int i = 0; i < 8; ++i) {
                float tmp = 0.9f * mem1[i];   // rounded mul
                tmp = tmp + cur1[i];          // rounded add
                float m = tmp - spk1[i];      // rounded sub
                mem1[i] = m;
                spk1[i] = (m > 1.0f) ? 1.0f : 0.0f;
            }
            uint4 pv;
            pv.x = pkspk(spk1[0], spk1[1]);   // lo=even h, hi=odd h
            pv.y = pkspk(spk1[2], spk1[3]);
            pv.z = pkspk(spk1[4], spk1[5]);
            pv.w = pkspk(spk1[6], spk1[7]);
            *(uint4*)(&pk[r * RSTR + j * 64 + q * 4]) = pv;
        }
        __syncthreads();

        // this thread: chains for t-slots {2tp, 2tp+1} of its (row, cls)
        float aE = 0.0f, aF = 0.0f;
        const unsigned int* srcT = &pk[brow * RSTR + (hihalf ? 128 : 0)];
        // v_fma_mix_f32: src0 = fp16 half of packed word (exact 0/1 -> f32),
        // src1 = f32 W2, src2 = f32 acc; single f32 rounding — bit-identical
        // to fmaf(spk, w, acc), h-ascending. LO=even h, HI=odd.
#define FMIX_LO(A, P, W) \
        asm("v_fma_mix_f32 %0, %1, %2, %0 op_sel_hi:[1,0,0]" \
            : "+v"(A) : "v"(P), "v"(W));
#define FMIX_HI(A, P, W) \
        asm("v_fma_mix_f32 %0, %1, %2, %0 op_sel:[1,0,0] op_sel_hi:[1,0,0]" \
            : "+v"(A) : "v"(P), "v"(W));
#define TR(A, P) \
        FMIX_LO(A, P.x, wA.x) FMIX_HI(A, P.x, wA.y) \
        FMIX_LO(A, P.y, wA.z) FMIX_HI(A, P.y, wA.w) \
        FMIX_LO(A, P.z, wB.x) FMIX_HI(A, P.z, wB.y) \
        FMIX_LO(A, P.w, wB.z) FMIX_HI(A, P.w, wB.w)
        #pragma unroll
        for (int gg = 0; gg < 16; ++gg) {
            const float4 wA = w2p[2 * gg];
            const float4 wB = w2p[2 * gg + 1];
            const uint4 ra = *(const uint4*)(srcT + 4 * gg);        // slot 2tp
            const uint4 rb = *(const uint4*)(srcT + 64 + 4 * gg);   // slot 2tp+1
            TR(aE, ra) TR(aF, rb)
        }
#undef TR
#undef FMIX_HI
#undef FMIX_LO
        __syncthreads();

        // exchange partner sums with the boring primitive: shfl_xor(32)
        // gives the lane±32 twin's value; selects order slots 0..3.
        const float pE = __shfl_xor(aE, 32, 64);
        const float pF = __shfl_xor(aF, 32, 64);
        const float t0 = hihalf ? pE : aE;   // slot 0 sum
        const float t1 = hihalf ? pF : aF;   // slot 1 sum
        const float t2 = hihalf ? aE : pE;   // slot 2 sum
        const float t3 = hihalf ? aF : pF;   // slot 3 sum
        const float aa[4] = {t0, t1, t2, t3};
        #pragma unroll
        for (int j = 0; j < 4; ++j) {
            const float c2 = aa[j] + b2c;
            float tt = 0.9f * m2; tt = tt + c2; m2 = tt - r2v;
            r2v = (m2 > 1.0f) ? 1.0f : 0.0f;
            o = o + r2v;
        }
    }

    if (lane < 32)   // tpair==0 twin writes (one writer per (row,cls))
        out[((size_t)blockIdx.x * ROWS + brow) * NCLS + bcls] = o;
}

extern "C" void kernel_launch(void* const* d_in, const int* in_sizes, int n_in,
                              void* d_out, int out_size, void* d_ws, size_t ws_size,
                              hipStream_t stream) {
    const float* x  = (const float*)d_in[0];
    const float* W1 = (const float*)d_in[1];
    const float* b1 = (const float*)d_in[2];
    const float* W2 = (const float*)d_in[3];
    const float* b2 = (const float*)d_in[4];
    float* out = (float*)d_out;
    (void)d_ws; (void)ws_size;

    const int batch = in_sizes[0] / IN_DIM;          // 16384
    snn_fused<<<batch / ROWS, THR, 0, stream>>>(x, W1, b1, W2, b2, out);
}

// Round 9
// 148.305 us; speedup vs baseline: 1.1682x; 1.0287x over previous
//
#include <hip/hip_runtime.h>
#include <math.h>

// TemporalSNNClassifier — bit-exact fp32 emulation (absmax 0.0 since r2).
//
// r23: software-pipelined phase-a/phase-b with double-buffered pk.
// r22 falsified the occupancy theory: 4 blocks/CU tripled bank conflicts
// (2.72M->9.47M) and REGRESSED (90->108us) — cross-wave LDS contention.
// Revert to r19-exact structure (2 blocks/CU, verified 90us). New lever:
// phase-a(g+1) (layer-1 leaky, pure VALU) has NO data dep on phase-b(g)
// (layer-2 GEMV, LDS-heavy) — mem1/spk1 evolve independently of mem2.
// Double-buffer pk (2x33.3KB = 66.6KB <= 80KB at 2 blocks/CU) and run
// a(g+1)->B || b(g)<-A in one barrier-free region, ONE barrier per group
// (protects write->read of B and read->overwrite of A). Barriers 32->16;
// phase-a VALU hides under phase-b LDS reads. Buffer offset 8320 words
// == 0 mod 32 -> identical bank behavior. Arithmetic order per chain
// unchanged -> absmax 0.0.
//
// Falsified ledger: w2 reads (r18 null), x-delivery (r19 null), pk
// lane-dedup (r20 NEG: spills), occupancy 4/CU (r22 NEG: conflicts 3.5x).
// r19: x via SMEM — kept. r17: fusion. r16b: fma_mix. Unified law
// (r10+r12+m136): 16B-per-lane VECTOR reads NEVER dedup; b32 same-addr
// broadcast FREE.
//
// FROZEN numerics: k-ascending single-accumulator fmaf chains (GEMM1),
// h-ascending 0..127 chain per (row,class,t) via v_fma_mix_f32 over fp16
// spike pairs (exact for {0,1}, single f32 rounding == fmaf(spk,w,acc)),
// bias as one separate add, leaky update ((0.9f*mem)+cur)-reset with
// contraction off, spike <=> mem > 1.0f, reset_t == spk_{t-1}.

#define T_STEPS 64
#define IN_DIM  256
#define HID     128
#define NCLS    8

#define ROWS   32     // rows per block (both phases)
#define THR    256
#define A_KQ   16     // float4 k-quads per chunk (64 k)
#define RSTR   260    // pk row stride (u32); =4 mod 32 -> staggered banks

typedef float f32x4 __attribute__((ext_vector_type(4)));

// pack two {0.0f,1.0f} spikes into one u32 as fp16 pair (lo=a, hi=b).
static __device__ __forceinline__ unsigned int pkspk(float a, float b) {
    auto h = __builtin_amdgcn_cvt_pkrtz(a, b);   // __fp16 ext_vector(2), 4B
    return __builtin_bit_cast(unsigned int, h);
}

__global__ __launch_bounds__(THR, 2)
void snn_fused(const float* __restrict__ x, const float* __restrict__ W1,
               const float* __restrict__ b1, const float* __restrict__ W2,
               const float* __restrict__ b2, float* __restrict__ out)
{
#pragma clang fp contract(off)
    __shared__ __align__(16) char smem[66560];
    float4 (* const w1c)[HID + 2] = (float4 (*)[HID + 2])smem;   // [16][130]
    unsigned int* const pkA = (unsigned int*)smem;               // 32*260 u32
    unsigned int* const pkB = (unsigned int*)(smem + 33280);     // 32*260 u32
    float*        const wsl = (float*)smem;                      // 32*128 f32

    const int tid  = threadIdx.x;
    const int lane = tid & 63;

    // ================= phase 1: cur1 GEMM (x via SMEM, r19 verbatim) =====
    {
        const int wv = __builtin_amdgcn_readfirstlane(tid >> 6);   // 0..3
        const size_t rowg0 = (size_t)blockIdx.x * ROWS;
        // per-wave x base: rows wv*8 .. wv*8+7 (uniform)
        const float* xb = x + (rowg0 + (size_t)wv * 8) * IN_DIM;

        float accL[8], accH[8];
        #pragma unroll
        for (int j = 0; j < 8; ++j) { accL[j] = 0.0f; accH[j] = 0.0f; }

        #pragma unroll 1
        for (int ch = 0; ch < 4; ++ch) {
            const int kbase = ch * (A_KQ * 4);
            // stage W1 chunk: 2048 float4, 8 per thread (coalesced per h-row)
            #pragma unroll
            for (int s = 0; s < 8; ++s) {
                const int idx = tid + s * THR;
                const int h = idx >> 4, kq = idx & 15;
                w1c[kq][h] = *(const float4*)(W1 + (size_t)h * IN_DIM + kbase + kq * 4);
            }
            __syncthreads();

            const float* xbc = xb + kbase;
            #pragma unroll 4
            for (int kq = 0; kq < A_KQ; ++kq) {
                // 8 rows' k-quads for this kq -> SGPRs (one wait for all 8).
                const float* xkq = xbc + kq * 4;
                f32x4 q0, q1, q2, q3, q4, q5, q6, q7;
                asm volatile(
                    "s_load_dwordx4 %0, %8, 0x0\n\t"
                    "s_load_dwordx4 %1, %8, 0x400\n\t"
                    "s_load_dwordx4 %2, %8, 0x800\n\t"
                    "s_load_dwordx4 %3, %8, 0xc00\n\t"
                    "s_load_dwordx4 %4, %8, 0x1000\n\t"
                    "s_load_dwordx4 %5, %8, 0x1400\n\t"
                    "s_load_dwordx4 %6, %8, 0x1800\n\t"
                    "s_load_dwordx4 %7, %8, 0x1c00\n\t"
                    "s_waitcnt lgkmcnt(0)"
                    : "=&s"(q0), "=&s"(q1), "=&s"(q2), "=&s"(q3),
                      "=&s"(q4), "=&s"(q5), "=&s"(q6), "=&s"(q7)
                    : "s"(xkq));

                const float4 wL = w1c[kq][lane];        // lane-contig 1KB
                const float4 wH = w1c[kq][64 + lane];
                // k ascending, single acc per (row, h) — order unchanged.
#define ROWFMA(J, XQ) { \
                float aL = accL[J], aH = accH[J]; \
                aL = fmaf(XQ.x, wL.x, aL); \
                aL = fmaf(XQ.y, wL.y, aL); \
                aL = fmaf(XQ.z, wL.z, aL); \
                aL = fmaf(XQ.w, wL.w, aL); \
                aH = fmaf(XQ.x, wH.x, aH); \
                aH = fmaf(XQ.y, wH.y, aH); \
                aH = fmaf(XQ.z, wH.z, aH); \
                aH = fmaf(XQ.w, wH.w, aH); \
                accL[J] = aL; accH[J] = aH; }
                ROWFMA(0, q0) ROWFMA(1, q1) ROWFMA(2, q2) ROWFMA(3, q3)
                ROWFMA(4, q4) ROWFMA(5, q5) ROWFMA(6, q6) ROWFMA(7, q7)
#undef ROWFMA
            }
            __syncthreads();   // w1c consumed before re-stage / alias
        }

        // handoff: cur1 tile -> LDS (aliases dead w1c). Values bit-identical
        // (same accL/accH + one rounded bias add).
        const float bL = b1[lane], bH = b1[64 + lane];
        #pragma unroll
        for (int j = 0; j < 8; ++j) {
            const int rr = wv * 8 + j;
            wsl[rr * HID + lane]      = accL[j] + bL;
            wsl[rr * HID + 64 + lane] = accH[j] + bH;
        }
    }

    // ================= phase 2: pipelined temporal loop ==================
    const int r = tid >> 3;            // phase-a row 0..31
    const int q = tid & 7;             // phase-a h-block

    const int brow = lane & 31;
    const int bcls = 2 * (tid >> 6) + (lane >> 5);
    const float b2c = b2[bcls];

    // W2 row for this thread's class (r19 path, verified).
    float4 w2r[32];
    {
        const float4* wg = (const float4*)(W2 + bcls * HID);
        #pragma unroll
        for (int g = 0; g < 32; ++g) w2r[g] = wg[g];
    }

    __syncthreads();   // wsl writes visible

    float cur1[16];
    {
        const float* src = wsl + r * HID + q * 16;
        #pragma unroll
        for (int i = 0; i < 4; ++i) {
            const float4 v = *(const float4*)(src + 4 * i);
            cur1[4*i+0] = v.x; cur1[4*i+1] = v.y;
            cur1[4*i+2] = v.z; cur1[4*i+3] = v.w;
        }
    }
    __syncthreads();   // cur1 read complete before pkA overwrites wsl region

    float mem1[16], spk1[16];
    #pragma unroll
    for (int i = 0; i < 16; ++i) { mem1[i] = 0.0f; spk1[i] = 0.0f; }
    float m2 = 0.0f, r2v = 0.0f, o = 0.0f;

    // one ts-group (4 timesteps) of layer-1: update mem1/spk1, pack to BUF
#define PHASE_A(BUF) \
    _Pragma("unroll") \
    for (int j = 0; j < 4; ++j) { \
        _Pragma("unroll") \
        for (int i = 0; i < 16; ++i) { \
            float tmp = 0.9f * mem1[i];   /* rounded mul */ \
            tmp = tmp + cur1[i];          /* rounded add */ \
            float m = tmp - spk1[i];      /* rounded sub */ \
            mem1[i] = m; \
            spk1[i] = (m > 1.0f) ? 1.0f : 0.0f; \
        } \
        unsigned int* dst = &(BUF)[r * RSTR + j * 64 + q * 8]; \
        _Pragma("unroll") \
        for (int s = 0; s < 2; ++s) { \
            uint4 pv; \
            pv.x = pkspk(spk1[8*s+0], spk1[8*s+1]); \
            pv.y = pkspk(spk1[8*s+2], spk1[8*s+3]); \
            pv.z = pkspk(spk1[8*s+4], spk1[8*s+5]); \
            pv.w = pkspk(spk1[8*s+6], spk1[8*s+7]); \
            *(uint4*)(dst + 4 * s) = pv; \
        } \
    }

    PHASE_A(pkA);      // group 0
    __syncthreads();

    #pragma unroll 1
    for (int g = 0; g < 16; ++g) {
        unsigned int* const curb = (g & 1) ? pkB : pkA;
        unsigned int* const nxtb = (g & 1) ? pkA : pkB;

        // phase-a(g+1) -> nxtb: no data dep on phase-b(g); overlaps reads.
        if (g < 15) { PHASE_A(nxtb); }

        // phase-b(g) <- curb (r19 verbatim)
        float a0 = 0.0f, a1 = 0.0f, a2 = 0.0f, a3 = 0.0f;
        const unsigned int* src = &curb[brow * RSTR];
        // v_fma_mix_f32: src0 = fp16 half of packed word (exact 0/1 -> f32),
        // src1 = f32 W2, src2 = f32 acc; single f32 rounding — bit-identical
        // to fmaf(spk, w, acc), h-ascending. LO=even h, HI=odd.
#define FMIX_LO(A, P, W) \
        asm("v_fma_mix_f32 %0, %1, %2, %0 op_sel_hi:[1,0,0]" \
            : "+v"(A) : "v"(P), "v"(W));
#define FMIX_HI(A, P, W) \
        asm("v_fma_mix_f32 %0, %1, %2, %0 op_sel:[1,0,0] op_sel_hi:[1,0,0]" \
            : "+v"(A) : "v"(P), "v"(W));
#define TR(A, P) \
        FMIX_LO(A, P.x, wA.x) FMIX_HI(A, P.x, wA.y) \
        FMIX_LO(A, P.y, wA.z) FMIX_HI(A, P.y, wA.w) \
        FMIX_LO(A, P.z, wB.x) FMIX_HI(A, P.z, wB.y) \
        FMIX_LO(A, P.w, wB.z) FMIX_HI(A, P.w, wB.w)
        #pragma unroll
        for (int gg = 0; gg < 16; ++gg) {
            const float4 wA = w2r[2 * gg];
            const float4 wB = w2r[2 * gg + 1];
            const uint4 p0 = *(const uint4*)(src + 0 * 64 + 4 * gg);
            const uint4 p1 = *(const uint4*)(src + 1 * 64 + 4 * gg);
            const uint4 p2 = *(const uint4*)(src + 2 * 64 + 4 * gg);
            const uint4 p3 = *(const uint4*)(src + 3 * 64 + 4 * gg);
            TR(a0, p0) TR(a1, p1) TR(a2, p2) TR(a3, p3)
        }
#undef TR
#undef FMIX_HI
#undef FMIX_LO

        __syncthreads();   // a(g+1) writes done + b(g) reads done

        // layer-2 update (register-only, frozen chain)
        const float aa[4] = {a0, a1, a2, a3};
        #pragma unroll
        for (int j = 0; j < 4; ++j) {
            const float c2 = aa[j] + b2c;
            float t2 = 0.9f * m2; t2 = t2 + c2; m2 = t2 - r2v;
            r2v = (m2 > 1.0f) ? 1.0f : 0.0f;
            o = o + r2v;
        }
    }
#undef PHASE_A

    out[((size_t)blockIdx.x * ROWS + brow) * NCLS + bcls] = o;
}

extern "C" void kernel_launch(void* const* d_in, const int* in_sizes, int n_in,
                              void* d_out, int out_size, void* d_ws, size_t ws_size,
                              hipStream_t stream) {
    const float* x  = (const float*)d_in[0];
    const float* W1 = (const float*)d_in[1];
    const float* b1 = (const float*)d_in[2];
    const float* W2 = (const float*)d_in[3];
    const float* b2 = (const float*)d_in[4];
    float* out = (float*)d_out;
    (void)d_ws; (void)ws_size;

    const int batch = in_sizes[0] / IN_DIM;          // 16384
    snn_fused<<<batch / ROWS, THR, 0, stream>>>(x, W1, b1, W2, b2, out);
}